// Round 9
// baseline (300.900 us; speedup 1.0000x reference)
//
#include <hip/hip_runtime.h>
#include <hip/hip_bf16.h>
#include <math.h>

#define TSTEPS 128
#define HD 16      // GRU hidden
#define G3 48      // 3*H gates
#define AD 32      // 2*H attention dim
#define H1W 36     // h1 row width in halfs (72B, 8B-aligned)
#define CHUNK 32   // serial steps per gx-MFMA chunk
#define NCHUNK 4
#define RW 52      // ring row width in halfs (>=48!); 4 rows = 104 dw = +8 banks
#define RING_BYTES (2 * CHUNK * RW * 2)   // 6656 B, reused by attention scratch

#define SC1 1.44269504088896340736f   // log2(e)   : sigmoid prescale
#define SC2 2.88539008177792681472f   // 2*log2(e) : tanh prescale

typedef _Float16 h4 __attribute__((ext_vector_type(4)));
typedef _Float16 f16x8 __attribute__((ext_vector_type(8)));
typedef float f32x4 __attribute__((ext_vector_type(4)));

#if defined(__has_builtin)
#  if __has_builtin(__builtin_amdgcn_exp2f)
#    define EXP2F(x) __builtin_amdgcn_exp2f(x)
#  endif
#  if __has_builtin(__builtin_amdgcn_rcpf)
#    define RCPF(x) __builtin_amdgcn_rcpf(x)
#  endif
#endif
#ifndef EXP2F
#  define EXP2F(x) exp2f(x)
#endif
#ifndef RCPF
#  define RCPF(x) (1.0f / (x))
#endif

// broadcast lane k's float to all lanes (v_readlane -> SGPR operand)
__device__ __forceinline__ float rl(float v, int k) {
    return __uint_as_float(__builtin_amdgcn_readlane(__float_as_uint(v), k));
}
// tanh(x) with pre-scaled input u = 2*log2e*x
__device__ __forceinline__ float tanh_pre(float u) {
    return 1.0f - 2.0f * RCPF(EXP2F(u) + 1.0f);
}

// Guarded row-major MFMA fragment load (k = k0+e, 0 beyond D), scaled.
template<int D>
__device__ __forceinline__ f16x8 load_frag(const float* __restrict__ rowptr,
                                           int k0, float scale) {
    f16x8 f;
    #pragma unroll
    for (int e = 0; e < 8; ++e) {
        const int k = k0 + e;
        f[e] = (k < D) ? (_Float16)(rowptr[k] * scale) : (_Float16)0.0f;
    }
    return f;
}

// One block = one sequence. 128 threads = 2 waves (wave0 fwd, wave1 bwd).
// gx = x @ Wih^T on the matrix pipe (per-chunk, per-wave LDS ring, barrier-free
// by same-wave DS ordering). Serial loop keeps h entirely in registers: lane k
// owns h[k]; gh rebuilt via v_readlane broadcasts (no LDS RAW chain). The h1
// history write is a pure sink (read only by the attention phase).
template<int D, bool HAS_PROJ>
__global__ __launch_bounds__(128, 6)
void gru_attn_kernel(
    const float* __restrict__ x,                      // [S, TSTEPS, D]
    const float* __restrict__ Wih_f, const float* __restrict__ Whh_f,
    const float* __restrict__ bih_f, const float* __restrict__ bhh_f,
    const float* __restrict__ Wih_b, const float* __restrict__ Whh_b,
    const float* __restrict__ bih_b, const float* __restrict__ bhh_b,
    const float* __restrict__ Wa, const float* __restrict__ ba,
    const float* __restrict__ ctxv,
    const float* __restrict__ Wm, const float* __restrict__ bm,
    float* __restrict__ out, int out_cols)
{
    __shared__ __align__(16) unsigned char smem_u[RING_BYTES];   // ring / attn scratch
    __shared__ __align__(16) _Float16 h1pool[TSTEPS * H1W];      // 9216 B
    __shared__ _Float16 dummypool[64];

    const int tid  = threadIdx.x;
    const int seq  = blockIdx.x;
    const int lane = tid & 63;
    const int wave = tid >> 6;

    // ---- Recurrence with chunked MFMA gx precompute ----
    {
        const int dirw = __builtin_amdgcn_readfirstlane(wave);   // wave-uniform
        const float* Wih = dirw ? Wih_b : Wih_f;
        const float* Whh = dirw ? Whh_b : Whh_f;
        const float* bihp = dirw ? bih_b : bih_f;
        const float* bhhp = dirw ? bhh_b : bhh_f;

        const int j  = lane;
        const int jc = (j < G3) ? j : (G3 - 1);      // clamped (extras harmless)
        const int fr = lane & 15;                    // fragment row/col
        const int k0 = ((lane >> 4) & 3) * 8;        // fragment k base
        const float scj = (jc < 2 * HD) ? SC1 : SC2; // this lane's gate prescale

        // recurrent weights f32 (prescaled) + biases (prescaled)
        float whhv[HD];
        #pragma unroll
        for (int k = 0; k < HD; ++k) whhv[k] = Whh[jc * HD + k] * scj;
        const float gb = bihp[jc] * scj;
        const float bh = bhhp[jc] * scj;

        // persistent B fragments: Wih rows (gates), prescaled per gate block
        f16x8 bfrag[3];
        #pragma unroll
        for (int n = 0; n < 3; ++n)
            bfrag[n] = load_frag<D>(Wih + (16 * n + fr) * D, k0, n < 2 ? SC1 : SC2);

        const float* xbase = x + (size_t)seq * TSTEPS * D;
        _Float16* myring = reinterpret_cast<_Float16*>(smem_u) + wave * CHUNK * RW;
        float h_own = 0.0f;          // lane k<16 holds h[k]; others garbage/unused

        // A fragments for chunk 0
        f16x8 afrag0, afrag1;
        {
            const int t0 = dirw ? (TSTEPS - 1 - fr) : fr;
            const int t1 = dirw ? (TSTEPS - 1 - (16 + fr)) : (16 + fr);
            afrag0 = load_frag<D>(xbase + t0 * D, k0, 1.0f);
            afrag1 = load_frag<D>(xbase + t1 * D, k0, 1.0f);
        }

        for (int c = 0; c < NCHUNK; ++c) {
            // gx via MFMA (matrix pipe) -> per-wave ring (bank-tiled rows)
            const int lsb0 = ((lane >> 4) & 3) * 4;
            #pragma unroll
            for (int n = 0; n < 3; ++n) {
                f32x4 accA = {0.f, 0.f, 0.f, 0.f};
                accA = __builtin_amdgcn_mfma_f32_16x16x32_f16(afrag0, bfrag[n], accA, 0, 0, 0);
                #pragma unroll
                for (int q = 0; q < 4; ++q)
                    myring[(lsb0 + q) * RW + 16 * n + fr] = (_Float16)accA[q];
                f32x4 accB = {0.f, 0.f, 0.f, 0.f};
                accB = __builtin_amdgcn_mfma_f32_16x16x32_f16(afrag1, bfrag[n], accB, 0, 0, 0);
                #pragma unroll
                for (int q = 0; q < 4; ++q)
                    myring[(16 + lsb0 + q) * RW + 16 * n + fr] = (_Float16)accB[q];
            }
            // prefetch next chunk's A fragments (covered by 32 serial steps)
            if (c + 1 < NCHUNK) {
                const int s0 = 32 * (c + 1) + fr;
                const int s1 = s0 + 16;
                const int t0 = dirw ? (TSTEPS - 1 - s0) : s0;
                const int t1 = dirw ? (TSTEPS - 1 - s1) : s1;
                afrag0 = load_frag<D>(xbase + t0 * D, k0, 1.0f);
                afrag1 = load_frag<D>(xbase + t1 * D, k0, 1.0f);
            }

            // serial 32 steps (ring writes precede reads: same-wave DS order)
            #pragma unroll 4
            for (int ls = 0; ls < CHUNK; ++ls) {
                const int s = 32 * c + ls;
                const int t = dirw ? (TSTEPS - 1 - s) : s;
                const float gxv = gb + (float)myring[ls * RW + jc];

                float ghv;
                if (s == 0) {
                    ghv = bh;
                } else {
                    // gh = bhh + Whh[j,:] . h  (h via readlane broadcasts)
                    float b0 = bh, b1 = 0.f, b2 = 0.f, b3 = 0.f;
                    #pragma unroll
                    for (int k = 0; k < HD; k += 4) {
                        b0 += whhv[k + 0] * rl(h_own, k + 0);
                        b1 += whhv[k + 1] * rl(h_own, k + 1);
                        b2 += whhv[k + 2] * rl(h_own, k + 2);
                        b3 += whhv[k + 3] * rl(h_own, k + 3);
                    }
                    ghv = (b0 + b1) + (b2 + b3);
                }

                // lanes 0..15: r | 16..31: z | 32..47: n   (inputs pre-scaled)
                const float y    = gxv + ghv;
                const float sact = RCPF(1.0f + EXP2F(-y));    // sigmoid (r,z)
                const float r    = __shfl_xor(sact, 32);      // n-lanes fetch r
                const float nv   = tanh_pre(gxv + r * ghv);   // n-lanes
                const float z    = __shfl_xor(sact, 16);      // h-lanes fetch z
                const float nn   = __shfl_xor(nv, 32);        // h-lanes fetch n
                const float hnew = nn + z * (h_own - nn);
                h_own = hnew;                                 // valid in lanes<16
                _Float16* wp = (lane < HD) ? &h1pool[t * H1W + dirw * HD + lane]
                                           : &dummypool[lane];
                *wp = (_Float16)hnew;                         // pure sink
            }
        }
    }
    __syncthreads();

    // attention scratch overlays the (now dead) ring
    float* w_sh = reinterpret_cast<float*>(smem_u);            // 512 B
    float* red  = reinterpret_cast<float*>(smem_u + 512);      // 16 B
    float* cvp  = reinterpret_cast<float*>(smem_u + 528);      // 4*32*4 B

    // ---- Attention: tanh proj -> softmax over t -> weighted sum ----
    {
        const int t = tid;
        float hh[AD];
        const h4* hr = reinterpret_cast<const h4*>(&h1pool[t * H1W]);
        #pragma unroll
        for (int p = 0; p < AD / 4; ++p) {
            const h4 v = hr[p];
            #pragma unroll
            for (int e = 0; e < 4; ++e) hh[4 * p + e] = (float)v[e];
        }
        float st = 0.0f;
        for (int i = 0; i < AD; ++i) {
            float a0 = ba[i], a1 = 0.f;
            const float* war = &Wa[i * AD];
            #pragma unroll
            for (int k = 0; k < AD; k += 2) {
                a0 += war[k] * hh[k];
                a1 += war[k + 1] * hh[k + 1];
            }
            st += tanh_pre(SC2 * (a0 + a1)) * ctxv[i];
        }
        // softmax across the 128 threads (2 waves)
        float m = st;
        #pragma unroll
        for (int off = 32; off > 0; off >>= 1) m = fmaxf(m, __shfl_xor(m, off));
        if (lane == 0) red[wave] = m;
        __syncthreads();
        m = fmaxf(red[0], red[1]);
        const float e = EXP2F(SC1 * (st - m));
        float ssum = e;
        #pragma unroll
        for (int off = 32; off > 0; off >>= 1) ssum += __shfl_xor(ssum, off);
        if (lane == 0) red[2 + wave] = ssum;
        __syncthreads();
        const float Z = red[2] + red[3];
        w_sh[t] = e * RCPF(Z);
    }
    __syncthreads();

    // cv[i] = sum_t w[t] * h1[t][i]   (4 partial groups of 32 t's each)
    {
        const int g = tid >> 5, i = tid & 31;
        float acc = 0.0f;
        for (int tt = g * 32; tt < g * 32 + 32; ++tt)
            acc += w_sh[tt] * (float)h1pool[tt * H1W + i];
        cvp[g * AD + i] = acc;
    }
    __syncthreads();
    if (tid < AD)
        cvp[tid] = cvp[tid] + cvp[AD + tid] + cvp[2 * AD + tid] + cvp[3 * AD + tid];
    __syncthreads();

    if (HAS_PROJ) {
        if (tid < 16) {
            float acc = bm[tid];
            #pragma unroll
            for (int i = 0; i < AD; ++i) acc += Wm[tid * AD + i] * cvp[i];
            out[(size_t)seq * out_cols + tid] = acc;
        }
    } else {
        if (tid < AD) out[(size_t)seq * out_cols + tid] = cvp[tid];
    }
}

extern "C" void kernel_launch(void* const* d_in, const int* in_sizes, int n_in,
                              void* d_out, int out_size, void* d_ws, size_t ws_size,
                              hipStream_t stream) {
    const float* x     = (const float*)d_in[0];
    const float* Wih1f = (const float*)d_in[1];
    const float* Whh1f = (const float*)d_in[2];
    const float* bih1f = (const float*)d_in[3];
    const float* bhh1f = (const float*)d_in[4];
    const float* Wih1b = (const float*)d_in[5];
    const float* Whh1b = (const float*)d_in[6];
    const float* bih1b = (const float*)d_in[7];
    const float* bhh1b = (const float*)d_in[8];
    const float* Wih2f = (const float*)d_in[9];
    const float* Whh2f = (const float*)d_in[10];
    const float* bih2f = (const float*)d_in[11];
    const float* bhh2f = (const float*)d_in[12];
    const float* Wih2b = (const float*)d_in[13];
    const float* Whh2b = (const float*)d_in[14];
    const float* bih2b = (const float*)d_in[15];
    const float* bhh2b = (const float*)d_in[16];
    const float* Wa1   = (const float*)d_in[17];
    const float* ba1   = (const float*)d_in[18];
    const float* ctx1  = (const float*)d_in[19];
    const float* Wa2   = (const float*)d_in[20];
    const float* ba2   = (const float*)d_in[21];
    const float* ctx2  = (const float*)d_in[22];
    const float* Wm    = (const float*)d_in[23];
    const float* bm    = (const float*)d_in[24];

    float* flow = (float*)d_ws;          // [8192, 16]
    float* outp = (float*)d_out;         // [64, 32]

    // Stage 1: 8192 sequences (B*N), D=25
    gru_attn_kernel<25, true><<<8192, 128, 0, stream>>>(
        x, Wih1f, Whh1f, bih1f, bhh1f, Wih1b, Whh1b, bih1b, bhh1b,
        Wa1, ba1, ctx1, Wm, bm, flow, 16);

    // Stage 2: 64 sequences (B), input = flow viewed as [64, 128, 16]
    gru_attn_kernel<16, false><<<64, 128, 0, stream>>>(
        flow, Wih2f, Whh2f, bih2f, bhh2f, Wih2b, Whh2b, bih2b, bhh2b,
        Wa2, ba2, ctx2, nullptr, nullptr, outp, 32);
}

// Round 10
// 226.712 us; speedup vs baseline: 1.3272x; 1.3272x over previous
//
#include <hip/hip_runtime.h>
#include <hip/hip_bf16.h>
#include <math.h>

#define TSTEPS 128
#define HD 16      // GRU hidden
#define G3 48      // 3*H gates
#define AD 32      // 2*H attention dim
#define H1ROW 16   // h1 history row: 16 halfs = 32B (16B-aligned, broadcast reads)
#define CHUNK 16   // serial steps per gx-MFMA chunk
#define NCHUNK 8
#define RW 52      // ring row width in halfs (>=48); 4 rows = 104 dw = +8 banks
#define RING_BYTES (2 * CHUNK * RW * 2)   // 3328 B, reused by attention scratch

#define SC1 1.44269504088896340736f   // log2(e)   : sigmoid prescale
#define SC2 2.88539008177792681472f   // 2*log2(e) : tanh prescale

typedef _Float16 h2 __attribute__((ext_vector_type(2)));
typedef _Float16 f16x8 __attribute__((ext_vector_type(8)));
typedef float f32x4 __attribute__((ext_vector_type(4)));

#if defined(__has_builtin)
#  if __has_builtin(__builtin_amdgcn_exp2f)
#    define EXP2F(x) __builtin_amdgcn_exp2f(x)
#  endif
#  if __has_builtin(__builtin_amdgcn_rcpf)
#    define RCPF(x) __builtin_amdgcn_rcpf(x)
#  endif
#endif
#ifndef EXP2F
#  define EXP2F(x) exp2f(x)
#endif
#ifndef RCPF
#  define RCPF(x) (1.0f / (x))
#endif

// tanh(x) with pre-scaled input u = 2*log2e*x
__device__ __forceinline__ float tanh_pre(float u) {
    return 1.0f - 2.0f * RCPF(EXP2F(u) + 1.0f);
}

// Guarded row-major MFMA fragment load (k = k0+e, 0 beyond D), scaled.
template<int D>
__device__ __forceinline__ f16x8 load_frag(const float* __restrict__ rowptr,
                                           int k0, float scale) {
    f16x8 f;
    #pragma unroll
    for (int e = 0; e < 8; ++e) {
        const int k = k0 + e;
        f[e] = (k < D) ? (_Float16)(rowptr[k] * scale) : (_Float16)0.0f;
    }
    return f;
}

// One block = one sequence. 128 threads = 2 waves (wave0 fwd, wave1 bwd).
// gx = x @ Wih^T on the matrix pipe (per-16-step chunk, per-wave LDS ring,
// barrier-free by same-wave DS ordering). Serial loop: lane j<48 owns gate j,
// gh = fdot2 over the fp16 h history row (s-indexed so both dirs share
// immediate offsets; 32B rows -> broadcast b128 reads). Fully unrolled ->
// all DS ops use immediate offsets.
template<int D, bool HAS_PROJ>
__global__ __launch_bounds__(128, 6)
void gru_attn_kernel(
    const float* __restrict__ x,                      // [S, TSTEPS, D]
    const float* __restrict__ Wih_f, const float* __restrict__ Whh_f,
    const float* __restrict__ bih_f, const float* __restrict__ bhh_f,
    const float* __restrict__ Wih_b, const float* __restrict__ Whh_b,
    const float* __restrict__ bih_b, const float* __restrict__ bhh_b,
    const float* __restrict__ Wa, const float* __restrict__ ba,
    const float* __restrict__ ctxv,
    const float* __restrict__ Wm, const float* __restrict__ bm,
    float* __restrict__ out, int out_cols)
{
    __shared__ __align__(16) unsigned char smem_u[RING_BYTES];    // ring / attn scratch
    __shared__ __align__(16) _Float16 h1pool[2][TSTEPS][H1ROW];   // 8192 B, s-indexed

    const int tid  = threadIdx.x;
    const int seq  = blockIdx.x;
    const int lane = tid & 63;
    const int wave = tid >> 6;

    // ---- Recurrence with chunked MFMA gx precompute ----
    {
        const int dirw = __builtin_amdgcn_readfirstlane(wave);   // wave-uniform
        const float* Wih = dirw ? Wih_b : Wih_f;
        const float* Whh = dirw ? Whh_b : Whh_f;
        const float* bihp = dirw ? bih_b : bih_f;
        const float* bhhp = dirw ? bhh_b : bhh_f;

        const int jc = (lane < G3) ? lane : (G3 - 1);   // clamped gate index
        const int fr = lane & 15;                       // fragment row/col
        const int k0 = ((lane >> 4) & 3) * 8;           // fragment k base
        const float scj = (jc < 2 * HD) ? SC1 : SC2;    // gate prescale

        // recurrent weights fp16 (prescaled) + biases (prescaled)
        h2 whhv[HD / 2];
        #pragma unroll
        for (int k = 0; k < HD; ++k)
            whhv[k >> 1][k & 1] = (_Float16)(Whh[jc * HD + k] * scj);
        const float gb = bihp[jc] * scj;
        const float bh = bhhp[jc] * scj;

        // persistent B fragments: Wih rows (gates), prescaled per gate block
        f16x8 bfrag[3];
        #pragma unroll
        for (int n = 0; n < 3; ++n)
            bfrag[n] = load_frag<D>(Wih + (16 * n + fr) * D, k0, n < 2 ? SC1 : SC2);

        const float* xbase = x + (size_t)seq * TSTEPS * D;
        _Float16* myring = reinterpret_cast<_Float16*>(smem_u) + wave * CHUNK * RW;
        const _Float16* ringrd = myring + jc;                    // + imm ls*RW
        _Float16* rw_ = myring + (((lane >> 4) & 3) * 4) * RW + fr;  // + imm (q*RW+16n)

        float h_own = 0.0f;          // lane k<16 holds h[k]

        // A fragment for chunk 0
        f16x8 afrag;
        {
            const int t0 = dirw ? (TSTEPS - 1 - fr) : fr;
            afrag = load_frag<D>(xbase + t0 * D, k0, 1.0f);
        }

        for (int c = 0; c < NCHUNK; ++c) {
            // gx via MFMA (matrix pipe) -> per-wave ring (bank-tiled rows)
            #pragma unroll
            for (int n = 0; n < 3; ++n) {
                f32x4 acc = {0.f, 0.f, 0.f, 0.f};
                acc = __builtin_amdgcn_mfma_f32_16x16x32_f16(afrag, bfrag[n], acc, 0, 0, 0);
                #pragma unroll
                for (int q = 0; q < 4; ++q)
                    rw_[q * RW + 16 * n] = (_Float16)acc[q];     // imm offsets
            }
            // prefetch next chunk's A fragment (hidden under 16 serial steps)
            f16x8 afrag_n;
            if (c + 1 < NCHUNK) {
                const int sA = (c + 1) * CHUNK + fr;
                const int tA = dirw ? (TSTEPS - 1 - sA) : sA;
                afrag_n = load_frag<D>(xbase + tA * D, k0, 1.0f);
            }

            // serial 16 steps, fully unrolled (imm DS offsets)
            // prev-h base: row (c*CHUNK - 1); deref only when s>0
            const _Float16* hprev = &h1pool[dirw][0][0] + (c * CHUNK - 1) * H1ROW;
            _Float16* hwr = &h1pool[dirw][c * CHUNK][lane & 15];

            #pragma unroll
            for (int ls = 0; ls < CHUNK; ++ls) {
                const float gxv = gb + (float)ringrd[ls * RW];

                float ghv;
                if (ls == 0 && c == 0) {                 // only step 0 (runtime c==0)
                    ghv = bh;
                } else {
                    const f16x8 hA = *reinterpret_cast<const f16x8*>(hprev + ls * H1ROW);
                    const f16x8 hB = *reinterpret_cast<const f16x8*>(hprev + ls * H1ROW + 8);
                    float b0 = bh, b1 = 0.f;
                    b0 = __builtin_amdgcn_fdot2(whhv[0], (h2){hA[0], hA[1]}, b0, false);
                    b1 = __builtin_amdgcn_fdot2(whhv[1], (h2){hA[2], hA[3]}, b1, false);
                    b0 = __builtin_amdgcn_fdot2(whhv[2], (h2){hA[4], hA[5]}, b0, false);
                    b1 = __builtin_amdgcn_fdot2(whhv[3], (h2){hA[6], hA[7]}, b1, false);
                    b0 = __builtin_amdgcn_fdot2(whhv[4], (h2){hB[0], hB[1]}, b0, false);
                    b1 = __builtin_amdgcn_fdot2(whhv[5], (h2){hB[2], hB[3]}, b1, false);
                    b0 = __builtin_amdgcn_fdot2(whhv[6], (h2){hB[4], hB[5]}, b0, false);
                    b1 = __builtin_amdgcn_fdot2(whhv[7], (h2){hB[6], hB[7]}, b1, false);
                    ghv = b0 + b1;
                }

                // lanes 0..15: r | 16..31: z | 32..47: n   (inputs pre-scaled)
                const float y    = gxv + ghv;
                const float sact = RCPF(1.0f + EXP2F(-y));    // sigmoid (r,z)
                const float r    = __shfl_xor(sact, 32);      // n-lanes fetch r
                const float nv   = tanh_pre(gxv + r * ghv);   // n-lanes
                const float z    = __shfl_xor(sact, 16);      // h-lanes fetch z
                const float nn   = __shfl_xor(nv, 32);        // h-lanes fetch n
                const float hnew = nn + z * (h_own - nn);
                h_own = hnew;                                 // valid in lanes<16
                if (lane < HD)
                    hwr[ls * H1ROW] = (_Float16)hnew;         // imm offset, pure sink
            }
            afrag = afrag_n;
        }
    }
    __syncthreads();

    // attention scratch overlays the (now dead) ring
    float* w_sh = reinterpret_cast<float*>(smem_u);            // 512 B
    float* red  = reinterpret_cast<float*>(smem_u + 512);      // 16 B
    float* cvp  = reinterpret_cast<float*>(smem_u + 528);      // 512 B

    // ---- Attention: tanh proj -> softmax over t -> weighted sum ----
    // h1[t][0..15] = fwd (s=t), h1[t][16..31] = bwd (s=127-t)
    {
        const int t = tid;
        float hh[AD];
        {
            const f16x8* fp = reinterpret_cast<const f16x8*>(&h1pool[0][t][0]);
            const f16x8* bp = reinterpret_cast<const f16x8*>(&h1pool[1][TSTEPS - 1 - t][0]);
            const f16x8 f0 = fp[0], f1 = fp[1], b0v = bp[0], b1v = bp[1];
            #pragma unroll
            for (int e = 0; e < 8; ++e) {
                hh[e]      = (float)f0[e];
                hh[8 + e]  = (float)f1[e];
                hh[16 + e] = (float)b0v[e];
                hh[24 + e] = (float)b1v[e];
            }
        }
        float st = 0.0f;
        for (int i = 0; i < AD; ++i) {
            float a0 = ba[i], a1 = 0.f;
            const float* war = &Wa[i * AD];
            #pragma unroll
            for (int k = 0; k < AD; k += 2) {
                a0 += war[k] * hh[k];
                a1 += war[k + 1] * hh[k + 1];
            }
            st += tanh_pre(SC2 * (a0 + a1)) * ctxv[i];
        }
        // softmax across the 128 threads (2 waves)
        float m = st;
        #pragma unroll
        for (int off = 32; off > 0; off >>= 1) m = fmaxf(m, __shfl_xor(m, off));
        if (lane == 0) red[wave] = m;
        __syncthreads();
        m = fmaxf(red[0], red[1]);
        const float e = EXP2F(SC1 * (st - m));
        float ssum = e;
        #pragma unroll
        for (int off = 32; off > 0; off >>= 1) ssum += __shfl_xor(ssum, off);
        if (lane == 0) red[2 + wave] = ssum;
        __syncthreads();
        const float Z = red[2] + red[3];
        w_sh[tid] = e * RCPF(Z);
    }
    __syncthreads();

    // cv[i] = sum_t w[t] * h1[t][i]   (4 partial groups of 32 t's each)
    {
        const int g = tid >> 5, i = tid & 31;
        const _Float16* p;
        int stp;
        if (i < HD) { p = &h1pool[0][g * 32][i];                 stp =  H1ROW; }
        else        { p = &h1pool[1][TSTEPS - 1 - g * 32][i - HD]; stp = -H1ROW; }
        float acc = 0.0f;
        for (int k = 0; k < 32; ++k) {
            acc += w_sh[g * 32 + k] * (float)(*p);
            p += stp;
        }
        cvp[g * AD + i] = acc;
    }
    __syncthreads();
    if (tid < AD)
        cvp[tid] = cvp[tid] + cvp[AD + tid] + cvp[2 * AD + tid] + cvp[3 * AD + tid];
    __syncthreads();

    if (HAS_PROJ) {
        if (tid < 16) {
            float acc = bm[tid];
            #pragma unroll
            for (int i = 0; i < AD; ++i) acc += Wm[tid * AD + i] * cvp[i];
            out[(size_t)seq * out_cols + tid] = acc;
        }
    } else {
        if (tid < AD) out[(size_t)seq * out_cols + tid] = cvp[tid];
    }
}

extern "C" void kernel_launch(void* const* d_in, const int* in_sizes, int n_in,
                              void* d_out, int out_size, void* d_ws, size_t ws_size,
                              hipStream_t stream) {
    const float* x     = (const float*)d_in[0];
    const float* Wih1f = (const float*)d_in[1];
    const float* Whh1f = (const float*)d_in[2];
    const float* bih1f = (const float*)d_in[3];
    const float* bhh1f = (const float*)d_in[4];
    const float* Wih1b = (const float*)d_in[5];
    const float* Whh1b = (const float*)d_in[6];
    const float* bih1b = (const float*)d_in[7];
    const float* bhh1b = (const float*)d_in[8];
    const float* Wih2f = (const float*)d_in[9];
    const float* Whh2f = (const float*)d_in[10];
    const float* bih2f = (const float*)d_in[11];
    const float* bhh2f = (const float*)d_in[12];
    const float* Wih2b = (const float*)d_in[13];
    const float* Whh2b = (const float*)d_in[14];
    const float* bih2b = (const float*)d_in[15];
    const float* bhh2b = (const float*)d_in[16];
    const float* Wa1   = (const float*)d_in[17];
    const float* ba1   = (const float*)d_in[18];
    const float* ctx1  = (const float*)d_in[19];
    const float* Wa2   = (const float*)d_in[20];
    const float* ba2   = (const float*)d_in[21];
    const float* ctx2  = (const float*)d_in[22];
    const float* Wm    = (const float*)d_in[23];
    const float* bm    = (const float*)d_in[24];

    float* flow = (float*)d_ws;          // [8192, 16]
    float* outp = (float*)d_out;         // [64, 32]

    // Stage 1: 8192 sequences (B*N), D=25
    gru_attn_kernel<25, true><<<8192, 128, 0, stream>>>(
        x, Wih1f, Whh1f, bih1f, bhh1f, Wih1b, Whh1b, bih1b, bhh1b,
        Wa1, ba1, ctx1, Wm, bm, flow, 16);

    // Stage 2: 64 sequences (B), input = flow viewed as [64, 128, 16]
    gru_attn_kernel<16, false><<<64, 128, 0, stream>>>(
        flow, Wih2f, Whh2f, bih2f, bhh2f, Wih2b, Whh2b, bih2b, bhh2b,
        Wa2, ba2, ctx2, nullptr, nullptr, outp, 32);
}